// Round 2
// baseline (219.672 us; speedup 1.0000x reference)
//
#include <hip/hip_runtime.h>
#include <hip/hip_bf16.h>

#define B_ 2
#define T_ 2048
#define C_ 1024
#define H_ 16
#define D_ 64

typedef __attribute__((ext_vector_type(8))) short bf16x8;
typedef __attribute__((ext_vector_type(4))) float f32x4;

static __device__ __forceinline__ float bf2f(unsigned short u) {
  union { unsigned int i; float f; } c;
  c.i = ((unsigned int)u) << 16;
  return c.f;
}
static __device__ __forceinline__ unsigned short f2bf(float f) {
  union { float f; unsigned int i; } c;
  c.f = f;
  unsigned int x = c.i;
  return (unsigned short)((x + 0x7fffu + ((x >> 16) & 1u)) >> 16);  // RNE
}

// async global->LDS, 16B per lane; LDS dest = (wave-uniform base) + lane*16
static __device__ __forceinline__ void gl_lds16(const void* g, void* s) {
  __builtin_amdgcn_global_load_lds(
      (const __attribute__((address_space(1))) void*)g,
      (__attribute__((address_space(3))) void*)s, 16, 0, 0);
}

// ---------------------------------------------------------------------------
__global__ __launch_bounds__(256) void fill_kernel_f32(float* __restrict__ out,
                                                       int n, float v) {
  int i = blockIdx.x * 256 + threadIdx.x;
  if (i < n) out[i] = v;
}

// ---------------------------------------------------------------------------
// fp32 -> bf16, 8 elems/thread, vectorized.
// ---------------------------------------------------------------------------
__global__ __launch_bounds__(256) void cvt_bf16(const float* __restrict__ X,
                                                unsigned short* __restrict__ Xb) {
  int i = (blockIdx.x * 256 + threadIdx.x) * 8;
  float4 f0 = *(const float4*)(X + i);
  float4 f1 = *(const float4*)(X + i + 4);
  union { unsigned short u[8]; uint4 v; } p;
  p.u[0] = f2bf(f0.x); p.u[1] = f2bf(f0.y); p.u[2] = f2bf(f0.z); p.u[3] = f2bf(f0.w);
  p.u[4] = f2bf(f1.x); p.u[5] = f2bf(f1.y); p.u[6] = f2bf(f1.z); p.u[7] = f2bf(f1.w);
  *(uint4*)(Xb + i) = p.v;
}

// ---------------------------------------------------------------------------
// Transpose + convert: W[K][N] fp32 -> WT[N][K] bf16. 32x32 LDS tiles.
// ---------------------------------------------------------------------------
__global__ __launch_bounds__(256) void transpose_cvt(const float* __restrict__ W,
                                                     unsigned short* __restrict__ WT,
                                                     int Kd, int Nd) {
  __shared__ float tile[32][33];
  const int n0 = blockIdx.x * 32, k0 = blockIdx.y * 32;
  const int tx = threadIdx.x & 31, ty = threadIdx.x >> 5;  // ty 0..7
#pragma unroll
  for (int i = 0; i < 4; ++i)
    tile[ty + i * 8][tx] = W[(size_t)(k0 + ty + i * 8) * Nd + n0 + tx];
  __syncthreads();
#pragma unroll
  for (int i = 0; i < 4; ++i)
    WT[(size_t)(n0 + ty + i * 8) * Kd + k0 + tx] = f2bf(tile[tx][ty + i * 8]);
}

// ---------------------------------------------------------------------------
// Per-head V transpose: vP[b*T+t][h*64+d] -> vT[((b*16+h)*64+d)*2048 + t].
// ---------------------------------------------------------------------------
__global__ __launch_bounds__(256) void v_transpose(const unsigned short* __restrict__ vP,
                                                   unsigned short* __restrict__ vT) {
  __shared__ unsigned short tile[64][72];
  const int t0 = blockIdx.x * 64;
  const int bh = blockIdx.y;
  const int b = bh >> 4;
  const int srow = threadIdx.x >> 3;       // 0..31
  const int sc8 = (threadIdx.x & 7) * 8;
#pragma unroll
  for (int it = 0; it < 2; ++it) {
    int r = srow + it * 32;
    *(uint4*)&tile[r][sc8] =
        *(const uint4*)(vP + (size_t)(b * T_ + t0 + r) * 1024 + (bh & 15) * 64 + sc8);
  }
  __syncthreads();
#pragma unroll
  for (int it = 0; it < 2; ++it) {
    int dd = srow + it * 32;
    union { unsigned short u[8]; uint4 v; } o;
#pragma unroll
    for (int j = 0; j < 8; ++j) o.u[j] = tile[sc8 + j][dd];
    *(uint4*)(vT + ((size_t)bh * 64 + dd) * 2048 + t0 + sc8) = o.v;
  }
}

// ---------------------------------------------------------------------------
// MFMA GEMM: C = A(bf16)[M,K] @ BT(bf16)[N,K]^T + bias.
// 128x128 tile, BK=64, 4 waves. Staging via global_load_lds width=16 (m97):
// wave w stages 32 rows of As and Bs per K-step (4 instrs each, 8 rows/instr).
// XOR swizzle preserved by permuting the per-lane GLOBAL fetch address
// (lane l fetches global chunk (l&7)^(r&7) -> lands at LDS chunk l&7);
// coalescing unaffected (same 128B row segment per 8-lane group).
// Frag reads: b128 at chunk (g+kk*4)^(row&7) -- conflict-free (0 in PMC).
// OUT_PLANES=1 -> bf16 q/k/v planes; else fp32 out.
// ---------------------------------------------------------------------------
template <int OUT_PLANES>
__global__ __launch_bounds__(256) void mfma_gemm(
    const unsigned short* __restrict__ A,
    const unsigned short* __restrict__ BT,
    const float* __restrict__ bias,
    unsigned short* __restrict__ qP, unsigned short* __restrict__ kP,
    unsigned short* __restrict__ vP, float* __restrict__ Fout,
    int N, int K) {
  __shared__ unsigned short As[128 * 64];
  __shared__ unsigned short Bs[128 * 64];

  const int tid = threadIdx.x;
  const int w = tid >> 6, lane = tid & 63;
  const int lo = lane & 15, g = lane >> 4;
  const int wm = (w >> 1) * 64, wn = (w & 1) * 64;
  const int m0 = blockIdx.y * 128, n0 = blockIdx.x * 128;

  // per-lane staging geometry: this lane covers row lr, swizzled chunk ls=lane&7,
  // fetching global chunk j = ls ^ (lr&7).
  const int lr8 = lane >> 3;           // row within the 8-row instr span

  const f32x4 zero4 = {0.f, 0.f, 0.f, 0.f};
  f32x4 acc[4][4] = {{zero4, zero4, zero4, zero4}, {zero4, zero4, zero4, zero4},
                     {zero4, zero4, zero4, zero4}, {zero4, zero4, zero4, zero4}};

  for (int k0 = 0; k0 < K; k0 += 64) {
    __syncthreads();  // previous iteration's frag readers done
#pragma unroll
    for (int it = 0; it < 4; ++it) {
      const int base_row = w * 32 + it * 8;       // wave-uniform
      const int r = base_row + lr8;               // this lane's row
      const int j = (lane & 7) ^ (r & 7);         // global chunk for LDS chunk lane&7
      gl_lds16(A + (size_t)(m0 + r) * K + k0 + j * 8, &As[base_row * 64]);
      gl_lds16(BT + (size_t)(n0 + r) * K + k0 + j * 8, &Bs[base_row * 64]);
    }
    __syncthreads();  // drains vmcnt -> staging visible

#pragma unroll
    for (int kk = 0; kk < 2; ++kk) {
      bf16x8 af[4], bfr[4];
#pragma unroll
      for (int i = 0; i < 4; ++i) {
        int ra = wm + i * 16 + lo;
        int rb = wn + i * 16 + lo;
        af[i]  = *(const bf16x8*)&As[ra * 64 + ((g + kk * 4) ^ (ra & 7)) * 8];
        bfr[i] = *(const bf16x8*)&Bs[rb * 64 + ((g + kk * 4) ^ (rb & 7)) * 8];
      }
#pragma unroll
      for (int i = 0; i < 4; ++i)
#pragma unroll
        for (int j = 0; j < 4; ++j)
          acc[i][j] = __builtin_amdgcn_mfma_f32_16x16x32_bf16(af[i], bfr[j],
                                                              acc[i][j], 0, 0, 0);
    }
  }

  float bv[4];
#pragma unroll
  for (int j = 0; j < 4; ++j) bv[j] = bias[n0 + wn + j * 16 + lo];

  if (OUT_PLANES) {
    const int pl = n0 >> 10;
    unsigned short* P = (pl == 0) ? qP : (pl == 1) ? kP : vP;
    const int col0 = (n0 & 1023) + wn + lo;
#pragma unroll
    for (int i = 0; i < 4; ++i)
#pragma unroll
      for (int r = 0; r < 4; ++r) {
        size_t row = (size_t)(m0 + wm + i * 16 + g * 4 + r);
#pragma unroll
        for (int j = 0; j < 4; ++j)
          P[row * 1024 + col0 + j * 16] = f2bf(acc[i][j][r] + bv[j]);
      }
  } else {
#pragma unroll
    for (int i = 0; i < 4; ++i)
#pragma unroll
      for (int r = 0; r < 4; ++r) {
        size_t row = (size_t)(m0 + wm + i * 16 + g * 4 + r);
#pragma unroll
        for (int j = 0; j < 4; ++j)
          Fout[row * N + n0 + wn + j * 16 + lo] = acc[i][j][r] + bv[j];
      }
  }
}

// ---------------------------------------------------------------------------
// RoPE in place on q/k planes; q pre-scaled by 1/8 (exact in bf16).
// ---------------------------------------------------------------------------
__global__ __launch_bounds__(256) void rope_kernel(unsigned short* __restrict__ qP,
                                                   unsigned short* __restrict__ kP) {
  int idx = blockIdx.x * 256 + threadIdx.x;
  int i = idx & 31;
  int h = (idx >> 5) & 15;
  int t = (idx >> 9) & 2047;
  int b = idx >> 20;
  float inv = exp2f((float)(-2 * i) * (13.287712379549449f / 64.0f));
  float ang = (float)t * inv;
  float s, c;
  sincosf(ang, &s, &c);
  size_t base = (size_t)(b * T_ + t) * 1024 + h * D_ + i;
  float q1 = bf2f(qP[base]);
  float q2 = bf2f(qP[base + 32]);
  qP[base]      = f2bf((q1 * c - q2 * s) * 0.125f);
  qP[base + 32] = f2bf((q2 * c + q1 * s) * 0.125f);
  float k1 = bf2f(kP[base]);
  float k2 = bf2f(kP[base + 32]);
  kP[base]      = f2bf(k1 * c - k2 * s);
  kP[base + 32] = f2bf(k2 * c + k1 * s);
}

// ---------------------------------------------------------------------------
// flash v5: verified v3 base (per-wave-private dataflow, identical staging /
// prefetch / barrier structure) with three wave-local changes:
//  * swapped QK^T within the wave: sacc[ct] = mfma(K_frag, Q_own) computes
//    S^T[k=ct*16+g*4+r][q=w*16+lo]. Same Ks read addresses/count as v3, but
//    the lane's 4 P-values are now column-consecutive -> P-write is one
//    ds_write_b64 per ct (2-way bank aliasing = free) instead of 16 scalar
//    4-way-conflicted ds_write_u16 (v3's 4.87M SQ_LDS_BANK_CONFLICT).
//  * each lane's q is fixed (w*16+lo) -> lsum is a single scalar; denominator
//    = 2 shfl_xor (over g) + per-r __shfl pickup. No LDS reduction needed.
//  * one q-tile per block (no half loop): grid 512->1024 blocks, 4 blocks/CU
//    for latency hiding. Per-block qP rows remain disjoint across blocks.
// PV, V^T staging, prefetch and the epilogue store are byte-identical to v3.
// ---------------------------------------------------------------------------
__global__ __launch_bounds__(256) void flash_mfma5(
    unsigned short* __restrict__ qP,
    const unsigned short* __restrict__ kP,
    const unsigned short* __restrict__ vT) {
  const int qt = blockIdx.x;   // 0..31
  const int bh = blockIdx.y;   // 0..31
  const int b = bh >> 4, h = bh & 15;
  const int tid = threadIdx.x;
  const int w = tid >> 6, lane = tid & 63;
  const int lo = lane & 15, g = lane >> 4;

  __shared__ unsigned short Ks[64][72];   // [key][d]
  __shared__ unsigned short VTs[64][72];  // [d][key]
  __shared__ unsigned short Ps[64][72];   // [q][key]

  const int srow = tid >> 3;        // 0..31
  const int sc8 = (tid & 7) * 8;
  const f32x4 zero4 = {0.f, 0.f, 0.f, 0.f};

  const int rowq0 = b * T_ + qt * 64;

  // Q fragments for this wave's 16 q-rows (B-operand of swapped QK).
  const unsigned short* qrow = qP + (size_t)(rowq0 + w * 16 + lo) * 1024 + h * 64;
  bf16x8 aq0 = *(const bf16x8*)(qrow + g * 8);
  bf16x8 aq1 = *(const bf16x8*)(qrow + 32 + g * 8);

  f32x4 oacc[4] = {zero4, zero4, zero4, zero4};  // O[q=w*16+g*4+r][d=c2*16+lo]
  float lsum = 0.f;                              // denom partial, q = w*16+lo

  uint4 kreg0, kreg1, vreg0, vreg1;
  {
    const size_t kb = (size_t)(b * T_ + srow) * 1024 + h * 64 + sc8;
    kreg0 = *(const uint4*)(kP + kb);
    kreg1 = *(const uint4*)(kP + kb + (size_t)32 * 1024);
    const size_t vb = ((size_t)bh * 64 + srow) * 2048 + sc8;
    vreg0 = *(const uint4*)(vT + vb);
    vreg1 = *(const uint4*)(vT + vb + (size_t)32 * 2048);
  }

  for (int kt = 0; kt <= qt; ++kt) {
    __syncthreads();
    *(uint4*)&Ks[srow][sc8]       = kreg0;
    *(uint4*)&Ks[srow + 32][sc8]  = kreg1;
    *(uint4*)&VTs[srow][sc8]      = vreg0;
    *(uint4*)&VTs[srow + 32][sc8] = vreg1;
    __syncthreads();
    if (kt < qt) {
      const size_t kb = (size_t)(b * T_ + (kt + 1) * 64 + srow) * 1024 + h * 64 + sc8;
      kreg0 = *(const uint4*)(kP + kb);
      kreg1 = *(const uint4*)(kP + kb + (size_t)32 * 1024);
      const size_t vb = ((size_t)bh * 64 + srow) * 2048 + (kt + 1) * 64 + sc8;
      vreg0 = *(const uint4*)(vT + vb);
      vreg1 = *(const uint4*)(vT + vb + (size_t)32 * 2048);
    }

    // ---- swapped QK^T: sacc[ct][r] = S^T[k=ct*16+g*4+r][q=w*16+lo]
    f32x4 sacc[4] = {zero4, zero4, zero4, zero4};
#pragma unroll
    for (int ct = 0; ct < 4; ++ct) {
      bf16x8 bk0 = *(const bf16x8*)&Ks[ct * 16 + lo][g * 8];
      bf16x8 bk1 = *(const bf16x8*)&Ks[ct * 16 + lo][32 + g * 8];
      sacc[ct] = __builtin_amdgcn_mfma_f32_16x16x32_bf16(bk0, aq0, sacc[ct], 0, 0, 0);
      sacc[ct] = __builtin_amdgcn_mfma_f32_16x16x32_bf16(bk1, aq1, sacc[ct], 0, 0, 0);
    }

    // ---- causal mask (diagonal tile only): local k > local q -> -inf
    if (kt == qt) {
#pragma unroll
      for (int ct = 0; ct < 4; ++ct)
#pragma unroll
        for (int r = 0; r < 4; ++r)
          if (ct * 16 + g * 4 + r > w * 16 + lo) sacc[ct][r] = -1e30f;
    }

    // ---- exp + lsum + vectorized P-write (k consecutive in-lane)
#pragma unroll
    for (int ct = 0; ct < 4; ++ct) {
      float p0 = __expf(sacc[ct][0]);
      float p1 = __expf(sacc[ct][1]);
      float p2 = __expf(sacc[ct][2]);
      float p3 = __expf(sacc[ct][3]);
      lsum += (p0 + p1) + (p2 + p3);
      unsigned int u0 = (unsigned int)f2bf(p0) | ((unsigned int)f2bf(p1) << 16);
      unsigned int u1 = (unsigned int)f2bf(p2) | ((unsigned int)f2bf(p3) << 16);
      uint2 pw; pw.x = u0; pw.y = u1;
      *(uint2*)&Ps[w * 16 + lo][ct * 16 + g * 4] = pw;
    }

    // ---- PV (unchanged from v3; same-wave Ps write->read, in-order DS)
    bf16x8 ap0 = *(const bf16x8*)&Ps[w * 16 + lo][g * 8];
    bf16x8 ap1 = *(const bf16x8*)&Ps[w * 16 + lo][32 + g * 8];
#pragma unroll
    for (int c2 = 0; c2 < 4; ++c2) {
      bf16x8 bv0 = *(const bf16x8*)&VTs[c2 * 16 + lo][g * 8];
      bf16x8 bv1 = *(const bf16x8*)&VTs[c2 * 16 + lo][32 + g * 8];
      oacc[c2] = __builtin_amdgcn_mfma_f32_16x16x32_bf16(ap0, bv0, oacc[c2], 0, 0, 0);
      oacc[c2] = __builtin_amdgcn_mfma_f32_16x16x32_bf16(ap1, bv1, oacc[c2], 0, 0, 0);
    }
  }

  // ---- denominator: reduce over g (lanes with same lo), then per-r pickup
  lsum += __shfl_xor(lsum, 16);
  lsum += __shfl_xor(lsum, 32);   // all lanes: full denom for q = w*16+lo

#pragma unroll
  for (int r = 0; r < 4; ++r) {
    float inv_r = 1.0f / __shfl(lsum, g * 4 + r);  // lane s holds q=w*16+s
    unsigned short* dst = qP + (size_t)(rowq0 + w * 16 + g * 4 + r) * 1024 + h * 64 + lo;
#pragma unroll
    for (int c2 = 0; c2 < 4; ++c2)
      dst[c2 * 16] = f2bf(oacc[c2][r] * inv_r);
  }
}

// ---------------------------------------------------------------------------
extern "C" void kernel_launch(void* const* d_in, const int* in_sizes, int n_in,
                              void* d_out, int out_size, void* d_ws, size_t ws_size,
                              hipStream_t stream) {
  const float *x = nullptr, *w_attn = nullptr, *b_attn = nullptr,
              *w_proj = nullptr, *b_proj = nullptr;
  for (int i = 0; i < n_in; ++i) {
    switch (in_sizes[i]) {
      case B_ * T_ * C_:  x      = (const float*)d_in[i]; break;
      case C_ * 3 * C_:   w_attn = (const float*)d_in[i]; break;
      case 3 * C_:        b_attn = (const float*)d_in[i]; break;
      case C_ * C_:       w_proj = (const float*)d_in[i]; break;
      case C_:            b_proj = (const float*)d_in[i]; break;
      default: break;
    }
  }
  float* out = (float*)d_out;
  const int nblk = (out_size + 255) / 256;

  if (!x || !w_attn || !b_attn || !w_proj || !b_proj) {
    fill_kernel_f32<<<nblk, 256, 0, stream>>>(out, out_size, 100.0f);  // SENTINEL
    return;
  }
  // ws >= 48 MB proven (rounds 10/11 fast path). Sentinel otherwise.
  if (ws_size < (size_t)48 * 1024 * 1024) {
    fill_kernel_f32<<<nblk, 256, 0, stream>>>(out, out_size, 50.0f);   // SENTINEL
    return;
  }

  // layout: q|k|v planes (24 MB) | vT (8) | xb (8) | waT (6) | wpT (2) = 48 MB
  unsigned short* qP  = (unsigned short*)d_ws;
  unsigned short* kP  = qP + (size_t)(B_ * T_) * 1024;
  unsigned short* vP  = kP + (size_t)(B_ * T_) * 1024;
  unsigned short* vT  = vP + (size_t)(B_ * T_) * 1024;
  unsigned short* xb  = vT + (size_t)(B_ * T_) * 1024;
  unsigned short* waT = xb + (size_t)(B_ * T_) * C_;
  unsigned short* wpT = waT + (size_t)C_ * 3 * C_;

  // 0) one-shot conversions: weights -> [N][K] bf16, x -> bf16
  transpose_cvt<<<dim3((3 * C_) / 32, C_ / 32), 256, 0, stream>>>(w_attn, waT, C_, 3 * C_);
  transpose_cvt<<<dim3(C_ / 32, C_ / 32), 256, 0, stream>>>(w_proj, wpT, C_, C_);
  cvt_bf16<<<(B_ * T_ * C_) / (256 * 8), 256, 0, stream>>>(x, xb);
  // 1) qkv = xb @ w_attn + b_attn (global_load_lds staging)
  mfma_gemm<1><<<dim3((3 * C_) / 128, (B_ * T_) / 128), 256, 0, stream>>>(
      xb, waT, b_attn, qP, kP, vP, nullptr, 3 * C_, C_);
  // 2) RoPE (q pre-scaled by 1/8)
  rope_kernel<<<(B_ * T_ * H_ * (D_ / 2)) / 256, 256, 0, stream>>>(qP, kP);
  // 3) V transpose for conflict-free flash staging
  v_transpose<<<dim3(T_ / 64, B_ * H_), 256, 0, stream>>>(vP, vT);
  // 4) causal flash attention v5 (swapped QK, vectorized P-write, 1 tile/block)
  flash_mfma5<<<dim3(32, B_ * H_), 256, 0, stream>>>(qP, kP, vT);
  // 5) out = y @ w_proj + b_proj (fp32 out)
  mfma_gemm<0><<<dim3(C_ / 128, (B_ * T_) / 128), 256, 0, stream>>>(
      qP, wpT, b_proj, nullptr, nullptr, nullptr, out, C_, C_);
}

// Round 3
// 196.660 us; speedup vs baseline: 1.1170x; 1.1170x over previous
//
#include <hip/hip_runtime.h>
#include <hip/hip_bf16.h>

#define B_ 2
#define T_ 2048
#define C_ 1024
#define H_ 16
#define D_ 64

typedef __attribute__((ext_vector_type(8))) short bf16x8;
typedef __attribute__((ext_vector_type(4))) float f32x4;

static __device__ __forceinline__ float bf2f(unsigned short u) {
  union { unsigned int i; float f; } c;
  c.i = ((unsigned int)u) << 16;
  return c.f;
}
static __device__ __forceinline__ unsigned short f2bf(float f) {
  union { float f; unsigned int i; } c;
  c.f = f;
  unsigned int x = c.i;
  return (unsigned short)((x + 0x7fffu + ((x >> 16) & 1u)) >> 16);  // RNE
}

// async global->LDS, 16B per lane; LDS dest = (wave-uniform base) + lane*16
static __device__ __forceinline__ void gl_lds16(const void* g, void* s) {
  __builtin_amdgcn_global_load_lds(
      (const __attribute__((address_space(1))) void*)g,
      (__attribute__((address_space(3))) void*)s, 16, 0, 0);
}

// ---------------------------------------------------------------------------
__global__ __launch_bounds__(256) void fill_kernel_f32(float* __restrict__ out,
                                                       int n, float v) {
  int i = blockIdx.x * 256 + threadIdx.x;
  if (i < n) out[i] = v;
}

// ---------------------------------------------------------------------------
// fp32 -> bf16, 8 elems/thread, vectorized.
// ---------------------------------------------------------------------------
__global__ __launch_bounds__(256) void cvt_bf16(const float* __restrict__ X,
                                                unsigned short* __restrict__ Xb) {
  int i = (blockIdx.x * 256 + threadIdx.x) * 8;
  float4 f0 = *(const float4*)(X + i);
  float4 f1 = *(const float4*)(X + i + 4);
  union { unsigned short u[8]; uint4 v; } p;
  p.u[0] = f2bf(f0.x); p.u[1] = f2bf(f0.y); p.u[2] = f2bf(f0.z); p.u[3] = f2bf(f0.w);
  p.u[4] = f2bf(f1.x); p.u[5] = f2bf(f1.y); p.u[6] = f2bf(f1.z); p.u[7] = f2bf(f1.w);
  *(uint4*)(Xb + i) = p.v;
}

// ---------------------------------------------------------------------------
// Transpose + convert: W[K][N] fp32 -> WT[N][K] bf16. 32x32 LDS tiles.
// ---------------------------------------------------------------------------
__global__ __launch_bounds__(256) void transpose_cvt(const float* __restrict__ W,
                                                     unsigned short* __restrict__ WT,
                                                     int Kd, int Nd) {
  __shared__ float tile[32][33];
  const int n0 = blockIdx.x * 32, k0 = blockIdx.y * 32;
  const int tx = threadIdx.x & 31, ty = threadIdx.x >> 5;  // ty 0..7
#pragma unroll
  for (int i = 0; i < 4; ++i)
    tile[ty + i * 8][tx] = W[(size_t)(k0 + ty + i * 8) * Nd + n0 + tx];
  __syncthreads();
#pragma unroll
  for (int i = 0; i < 4; ++i)
    WT[(size_t)(n0 + ty + i * 8) * Kd + k0 + tx] = f2bf(tile[tx][ty + i * 8]);
}

// ---------------------------------------------------------------------------
// Per-head V transpose: vP[b*T+t][h*64+d] -> vT[((b*16+h)*64+d)*2048 + t].
// ---------------------------------------------------------------------------
__global__ __launch_bounds__(256) void v_transpose(const unsigned short* __restrict__ vP,
                                                   unsigned short* __restrict__ vT) {
  __shared__ unsigned short tile[64][72];
  const int t0 = blockIdx.x * 64;
  const int bh = blockIdx.y;
  const int b = bh >> 4;
  const int srow = threadIdx.x >> 3;       // 0..31
  const int sc8 = (threadIdx.x & 7) * 8;
#pragma unroll
  for (int it = 0; it < 2; ++it) {
    int r = srow + it * 32;
    *(uint4*)&tile[r][sc8] =
        *(const uint4*)(vP + (size_t)(b * T_ + t0 + r) * 1024 + (bh & 15) * 64 + sc8);
  }
  __syncthreads();
#pragma unroll
  for (int it = 0; it < 2; ++it) {
    int dd = srow + it * 32;
    union { unsigned short u[8]; uint4 v; } o;
#pragma unroll
    for (int j = 0; j < 8; ++j) o.u[j] = tile[sc8 + j][dd];
    *(uint4*)(vT + ((size_t)bh * 64 + dd) * 2048 + t0 + sc8) = o.v;
  }
}

// ---------------------------------------------------------------------------
// MFMA GEMM: C = A(bf16)[M,K] @ BT(bf16)[N,K]^T + bias.
// 128x128 tile, BK=64, 4 waves. Staging via global_load_lds width=16 (m97):
// wave w stages 32 rows of As and Bs per K-step (4 instrs each, 8 rows/instr).
// XOR swizzle preserved by permuting the per-lane GLOBAL fetch address
// (lane l fetches global chunk (l&7)^(r&7) -> lands at LDS chunk l&7);
// coalescing unaffected (same 128B row segment per 8-lane group).
// Frag reads: b128 at chunk (g+kk*4)^(row&7) -- conflict-free (0 in PMC).
// OUT_PLANES=1 -> bf16 q/k/v planes; else fp32 out.
// ---------------------------------------------------------------------------
template <int OUT_PLANES>
__global__ __launch_bounds__(256) void mfma_gemm(
    const unsigned short* __restrict__ A,
    const unsigned short* __restrict__ BT,
    const float* __restrict__ bias,
    unsigned short* __restrict__ qP, unsigned short* __restrict__ kP,
    unsigned short* __restrict__ vP, float* __restrict__ Fout,
    int N, int K) {
  __shared__ unsigned short As[128 * 64];
  __shared__ unsigned short Bs[128 * 64];

  const int tid = threadIdx.x;
  const int w = tid >> 6, lane = tid & 63;
  const int lo = lane & 15, g = lane >> 4;
  const int wm = (w >> 1) * 64, wn = (w & 1) * 64;
  const int m0 = blockIdx.y * 128, n0 = blockIdx.x * 128;

  // per-lane staging geometry: this lane covers row lr, swizzled chunk ls=lane&7,
  // fetching global chunk j = ls ^ (lr&7).
  const int lr8 = lane >> 3;           // row within the 8-row instr span

  const f32x4 zero4 = {0.f, 0.f, 0.f, 0.f};
  f32x4 acc[4][4] = {{zero4, zero4, zero4, zero4}, {zero4, zero4, zero4, zero4},
                     {zero4, zero4, zero4, zero4}, {zero4, zero4, zero4, zero4}};

  for (int k0 = 0; k0 < K; k0 += 64) {
    __syncthreads();  // previous iteration's frag readers done
#pragma unroll
    for (int it = 0; it < 4; ++it) {
      const int base_row = w * 32 + it * 8;       // wave-uniform
      const int r = base_row + lr8;               // this lane's row
      const int j = (lane & 7) ^ (r & 7);         // global chunk for LDS chunk lane&7
      gl_lds16(A + (size_t)(m0 + r) * K + k0 + j * 8, &As[base_row * 64]);
      gl_lds16(BT + (size_t)(n0 + r) * K + k0 + j * 8, &Bs[base_row * 64]);
    }
    __syncthreads();  // drains vmcnt -> staging visible

#pragma unroll
    for (int kk = 0; kk < 2; ++kk) {
      bf16x8 af[4], bfr[4];
#pragma unroll
      for (int i = 0; i < 4; ++i) {
        int ra = wm + i * 16 + lo;
        int rb = wn + i * 16 + lo;
        af[i]  = *(const bf16x8*)&As[ra * 64 + ((g + kk * 4) ^ (ra & 7)) * 8];
        bfr[i] = *(const bf16x8*)&Bs[rb * 64 + ((g + kk * 4) ^ (rb & 7)) * 8];
      }
#pragma unroll
      for (int i = 0; i < 4; ++i)
#pragma unroll
        for (int j = 0; j < 4; ++j)
          acc[i][j] = __builtin_amdgcn_mfma_f32_16x16x32_bf16(af[i], bfr[j],
                                                              acc[i][j], 0, 0, 0);
    }
  }

  float bv[4];
#pragma unroll
  for (int j = 0; j < 4; ++j) bv[j] = bias[n0 + wn + j * 16 + lo];

  if (OUT_PLANES) {
    const int pl = n0 >> 10;
    unsigned short* P = (pl == 0) ? qP : (pl == 1) ? kP : vP;
    const int col0 = (n0 & 1023) + wn + lo;
#pragma unroll
    for (int i = 0; i < 4; ++i)
#pragma unroll
      for (int r = 0; r < 4; ++r) {
        size_t row = (size_t)(m0 + wm + i * 16 + g * 4 + r);
#pragma unroll
        for (int j = 0; j < 4; ++j)
          P[row * 1024 + col0 + j * 16] = f2bf(acc[i][j][r] + bv[j]);
      }
  } else {
#pragma unroll
    for (int i = 0; i < 4; ++i)
#pragma unroll
      for (int r = 0; r < 4; ++r) {
        size_t row = (size_t)(m0 + wm + i * 16 + g * 4 + r);
#pragma unroll
        for (int j = 0; j < 4; ++j)
          Fout[row * N + n0 + wn + j * 16 + lo] = acc[i][j][r] + bv[j];
      }
  }
}

// ---------------------------------------------------------------------------
// RoPE in place on q/k planes; q pre-scaled by 1/8 (exact in bf16).
// ---------------------------------------------------------------------------
__global__ __launch_bounds__(256) void rope_kernel(unsigned short* __restrict__ qP,
                                                   unsigned short* __restrict__ kP) {
  int idx = blockIdx.x * 256 + threadIdx.x;
  int i = idx & 31;
  int h = (idx >> 5) & 15;
  int t = (idx >> 9) & 2047;
  int b = idx >> 20;
  float inv = exp2f((float)(-2 * i) * (13.287712379549449f / 64.0f));
  float ang = (float)t * inv;
  float s, c;
  sincosf(ang, &s, &c);
  size_t base = (size_t)(b * T_ + t) * 1024 + h * D_ + i;
  float q1 = bf2f(qP[base]);
  float q2 = bf2f(qP[base + 32]);
  qP[base]      = f2bf((q1 * c - q2 * s) * 0.125f);
  qP[base + 32] = f2bf((q2 * c + q1 * s) * 0.125f);
  float k1 = bf2f(kP[base]);
  float k2 = bf2f(kP[base + 32]);
  kP[base]      = f2bf(k1 * c - k2 * s);
  kP[base + 32] = f2bf(k2 * c + k1 * s);
}

// ---------------------------------------------------------------------------
// flash v6 = v3's paired-tile structure (uniform 33 k-iters/block -- the
// property v5 lost; its removal cost +19us) + v5's verified wave-local
// improvements:
//  * swapped QK^T within the wave: sacc[ct] = mfma(K_frag, Q_own) computes
//    S^T[k=ct*16+g*4+r][q=w*16+lo]; lane's 4 P-values are column-consecutive
//    -> P-write is one ds_write_b64 per ct instead of 16 scalar ds_write_u16.
//  * lsum is a single scalar per lane (q fixed at w*16+lo); denominator via
//    2 shfl_xor + per-r __shfl pickup. No LDS reduction.
//  * s_setprio(1) around the two 8-MFMA clusters (T5, +4-7% on attn, m191).
// Staging, prefetch, barriers, epilogue stores: byte-identical to v3.
// ---------------------------------------------------------------------------
__global__ __launch_bounds__(256) void flash_mfma6(
    unsigned short* __restrict__ qP,
    const unsigned short* __restrict__ kP,
    const unsigned short* __restrict__ vT) {
  const int bx = blockIdx.x;   // 0..15
  const int bh = blockIdx.y;   // 0..31
  const int b = bh >> 4, h = bh & 15;
  const int tid = threadIdx.x;
  const int w = tid >> 6, lane = tid & 63;
  const int lo = lane & 15, g = lane >> 4;

  __shared__ unsigned short Ks[64][72];   // [key][d]
  __shared__ unsigned short VTs[64][72];  // [d][key]
  __shared__ unsigned short Ps[64][72];   // [q][key]

  const int srow = tid >> 3;        // 0..31
  const int sc8 = (tid & 7) * 8;
  const f32x4 zero4 = {0.f, 0.f, 0.f, 0.f};

#pragma unroll
  for (int half = 0; half < 2; ++half) {
    const int qt = half ? (31 - bx) : bx;
    const int rowq0 = b * T_ + qt * 64;

    // Q fragments for this wave's 16 q-rows (B-operand of swapped QK).
    const unsigned short* qrow = qP + (size_t)(rowq0 + w * 16 + lo) * 1024 + h * 64;
    bf16x8 aq0 = *(const bf16x8*)(qrow + g * 8);
    bf16x8 aq1 = *(const bf16x8*)(qrow + 32 + g * 8);

    f32x4 oacc[4] = {zero4, zero4, zero4, zero4};  // O[q=w*16+g*4+r][d=c2*16+lo]
    float lsum = 0.f;                              // denom partial, q = w*16+lo

    uint4 kreg0, kreg1, vreg0, vreg1;
    {
      const size_t kb = (size_t)(b * T_ + srow) * 1024 + h * 64 + sc8;
      kreg0 = *(const uint4*)(kP + kb);
      kreg1 = *(const uint4*)(kP + kb + (size_t)32 * 1024);
      const size_t vb = ((size_t)bh * 64 + srow) * 2048 + sc8;
      vreg0 = *(const uint4*)(vT + vb);
      vreg1 = *(const uint4*)(vT + vb + (size_t)32 * 2048);
    }

    for (int kt = 0; kt <= qt; ++kt) {
      __syncthreads();   // prior readers of Ks/VTs/Ps done
      *(uint4*)&Ks[srow][sc8]       = kreg0;
      *(uint4*)&Ks[srow + 32][sc8]  = kreg1;
      *(uint4*)&VTs[srow][sc8]      = vreg0;
      *(uint4*)&VTs[srow + 32][sc8] = vreg1;
      __syncthreads();   // staging visible
      if (kt < qt) {
        const size_t kb = (size_t)(b * T_ + (kt + 1) * 64 + srow) * 1024 + h * 64 + sc8;
        kreg0 = *(const uint4*)(kP + kb);
        kreg1 = *(const uint4*)(kP + kb + (size_t)32 * 1024);
        const size_t vb = ((size_t)bh * 64 + srow) * 2048 + (kt + 1) * 64 + sc8;
        vreg0 = *(const uint4*)(vT + vb);
        vreg1 = *(const uint4*)(vT + vb + (size_t)32 * 2048);
      }

      // ---- swapped QK^T: sacc[ct][r] = S^T[k=ct*16+g*4+r][q=w*16+lo]
      f32x4 sacc[4] = {zero4, zero4, zero4, zero4};
      __builtin_amdgcn_s_setprio(1);
#pragma unroll
      for (int ct = 0; ct < 4; ++ct) {
        bf16x8 bk0 = *(const bf16x8*)&Ks[ct * 16 + lo][g * 8];
        bf16x8 bk1 = *(const bf16x8*)&Ks[ct * 16 + lo][32 + g * 8];
        sacc[ct] = __builtin_amdgcn_mfma_f32_16x16x32_bf16(bk0, aq0, sacc[ct], 0, 0, 0);
        sacc[ct] = __builtin_amdgcn_mfma_f32_16x16x32_bf16(bk1, aq1, sacc[ct], 0, 0, 0);
      }
      __builtin_amdgcn_s_setprio(0);

      // ---- causal mask (diagonal tile only): local k > local q -> -inf
      if (kt == qt) {
#pragma unroll
        for (int ct = 0; ct < 4; ++ct)
#pragma unroll
          for (int r = 0; r < 4; ++r)
            if (ct * 16 + g * 4 + r > w * 16 + lo) sacc[ct][r] = -1e30f;
      }

      // ---- exp + lsum + vectorized P-write (k consecutive in-lane)
#pragma unroll
      for (int ct = 0; ct < 4; ++ct) {
        float p0 = __expf(sacc[ct][0]);
        float p1 = __expf(sacc[ct][1]);
        float p2 = __expf(sacc[ct][2]);
        float p3 = __expf(sacc[ct][3]);
        lsum += (p0 + p1) + (p2 + p3);
        unsigned int u0 = (unsigned int)f2bf(p0) | ((unsigned int)f2bf(p1) << 16);
        unsigned int u1 = (unsigned int)f2bf(p2) | ((unsigned int)f2bf(p3) << 16);
        uint2 pw; pw.x = u0; pw.y = u1;
        *(uint2*)&Ps[w * 16 + lo][ct * 16 + g * 4] = pw;
      }

      // ---- PV (same-wave Ps write->read, in-order DS pipe)
      bf16x8 ap0 = *(const bf16x8*)&Ps[w * 16 + lo][g * 8];
      bf16x8 ap1 = *(const bf16x8*)&Ps[w * 16 + lo][32 + g * 8];
      __builtin_amdgcn_s_setprio(1);
#pragma unroll
      for (int c2 = 0; c2 < 4; ++c2) {
        bf16x8 bv0 = *(const bf16x8*)&VTs[c2 * 16 + lo][g * 8];
        bf16x8 bv1 = *(const bf16x8*)&VTs[c2 * 16 + lo][32 + g * 8];
        oacc[c2] = __builtin_amdgcn_mfma_f32_16x16x32_bf16(ap0, bv0, oacc[c2], 0, 0, 0);
        oacc[c2] = __builtin_amdgcn_mfma_f32_16x16x32_bf16(ap1, bv1, oacc[c2], 0, 0, 0);
      }
      __builtin_amdgcn_s_setprio(0);
    }

    // ---- denominator: reduce over g (lanes with same lo), then per-r pickup
    lsum += __shfl_xor(lsum, 16);
    lsum += __shfl_xor(lsum, 32);   // lanes {lo,lo+16,lo+32,lo+48}: full denom

#pragma unroll
    for (int r = 0; r < 4; ++r) {
      float inv_r = 1.0f / __shfl(lsum, g * 4 + r);  // lane s holds q=w*16+s
      unsigned short* dst = qP + (size_t)(rowq0 + w * 16 + g * 4 + r) * 1024 + h * 64 + lo;
#pragma unroll
      for (int c2 = 0; c2 < 4; ++c2)
        dst[c2 * 16] = f2bf(oacc[c2][r] * inv_r);
    }
    // next half's first __syncthreads protects LDS reuse vs these stores
  }
}

// ---------------------------------------------------------------------------
extern "C" void kernel_launch(void* const* d_in, const int* in_sizes, int n_in,
                              void* d_out, int out_size, void* d_ws, size_t ws_size,
                              hipStream_t stream) {
  const float *x = nullptr, *w_attn = nullptr, *b_attn = nullptr,
              *w_proj = nullptr, *b_proj = nullptr;
  for (int i = 0; i < n_in; ++i) {
    switch (in_sizes[i]) {
      case B_ * T_ * C_:  x      = (const float*)d_in[i]; break;
      case C_ * 3 * C_:   w_attn = (const float*)d_in[i]; break;
      case 3 * C_:        b_attn = (const float*)d_in[i]; break;
      case C_ * C_:       w_proj = (const float*)d_in[i]; break;
      case C_:            b_proj = (const float*)d_in[i]; break;
      default: break;
    }
  }
  float* out = (float*)d_out;
  const int nblk = (out_size + 255) / 256;

  if (!x || !w_attn || !b_attn || !w_proj || !b_proj) {
    fill_kernel_f32<<<nblk, 256, 0, stream>>>(out, out_size, 100.0f);  // SENTINEL
    return;
  }
  // ws >= 48 MB proven (rounds 10/11 fast path). Sentinel otherwise.
  if (ws_size < (size_t)48 * 1024 * 1024) {
    fill_kernel_f32<<<nblk, 256, 0, stream>>>(out, out_size, 50.0f);   // SENTINEL
    return;
  }

  // layout: q|k|v planes (24 MB) | vT (8) | xb (8) | waT (6) | wpT (2) = 48 MB
  unsigned short* qP  = (unsigned short*)d_ws;
  unsigned short* kP  = qP + (size_t)(B_ * T_) * 1024;
  unsigned short* vP  = kP + (size_t)(B_ * T_) * 1024;
  unsigned short* vT  = vP + (size_t)(B_ * T_) * 1024;
  unsigned short* xb  = vT + (size_t)(B_ * T_) * 1024;
  unsigned short* waT = xb + (size_t)(B_ * T_) * C_;
  unsigned short* wpT = waT + (size_t)C_ * 3 * C_;

  // 0) one-shot conversions: weights -> [N][K] bf16, x -> bf16
  transpose_cvt<<<dim3((3 * C_) / 32, C_ / 32), 256, 0, stream>>>(w_attn, waT, C_, 3 * C_);
  transpose_cvt<<<dim3(C_ / 32, C_ / 32), 256, 0, stream>>>(w_proj, wpT, C_, C_);
  cvt_bf16<<<(B_ * T_ * C_) / (256 * 8), 256, 0, stream>>>(x, xb);
  // 1) qkv = xb @ w_attn + b_attn (global_load_lds staging)
  mfma_gemm<1><<<dim3((3 * C_) / 128, (B_ * T_) / 128), 256, 0, stream>>>(
      xb, waT, b_attn, qP, kP, vP, nullptr, 3 * C_, C_);
  // 2) RoPE (q pre-scaled by 1/8)
  rope_kernel<<<(B_ * T_ * H_ * (D_ / 2)) / 256, 256, 0, stream>>>(qP, kP);
  // 3) V transpose for conflict-free flash staging
  v_transpose<<<dim3(T_ / 64, B_ * H_), 256, 0, stream>>>(vP, vT);
  // 4) causal flash attention v6 (paired tiles + swapped QK + setprio)
  flash_mfma6<<<dim3(16, B_ * H_), 256, 0, stream>>>(qP, kP, vT);
  // 5) out = y @ w_proj + b_proj (fp32 out)
  mfma_gemm<0><<<dim3(C_ / 128, (B_ * T_) / 128), 256, 0, stream>>>(
      qP, wpT, b_proj, nullptr, nullptr, nullptr, out, C_, C_);
}